// Round 18
// baseline (178.662 us; speedup 1.0000x reference)
//
#include <hip/hip_runtime.h>

#define DI __device__ __forceinline__

// ---------------- ws layout (float offsets) ----------------
// umax: [0..255] slot0 plain-store buckets (|x|), [256..575] slots1-5 atomic buckets (64 each)
constexpr int OFF_W0KT = 576;     // 27*32 (k-major, conv0maxN)
constexpr int OFF_W0P  = 1440;    // 32*28 (padded oc-major, conv01n)
constexpr int OFF_W1I  = 2336;    // 4*32
constexpr int OFF_W2KT = 2464;    // 36*32 (k-major, conv2c)
constexpr int OFF_W3T  = 3616;    // 4*72*36 (phase-k-major, conv3)
constexpr int OFF_W4T  = 13984;   // 10368
constexpr int OFF_WDI  = 24352;   // 20480
constexpr int OFF_WSF0 = 44832;
constexpr int OFF_BNS0 = 44864;
constexpr int OFF_BNB0 = 44896;
constexpr int OFF_WSF1 = 44928;
constexpr int OFF_BNS1 = 44932;
constexpr int OFF_BNB1 = 44936;
constexpr int OFF_WSF2 = 44940;
constexpr int OFF_BNS2 = 44972;
constexpr int OFF_BNB2 = 45004;
constexpr int OFF_WSF3 = 45036;
constexpr int OFF_BNS3 = 45068;
constexpr int OFF_BNB3 = 45100;
constexpr int OFF_WSF4 = 45132;
constexpr int OFF_BNS4 = 45164;
constexpr int OFF_BNB4 = 45196;
constexpr int OFF_WSFD = 45228;   // 10
constexpr int OFF_LOG  = 45248;   // 10240
constexpr int OFF_ACT  = 55488;
constexpr long ACT_A_OFF = OFF_ACT;              // act2/act4
constexpr long ACT_B_OFF = OFF_ACT + 8388608L;   // act1/act3

// ---------------- helpers ----------------
DI float quantm(float x, float rsf) {
    float q = rintf(x * rsf);
    return fminf(fmaxf(q, -127.0f), 127.0f);
}
// slot 0: 256 plain-stored buckets
DI float get_sf0(const unsigned* umax) {
    unsigned m = 0u;
    #pragma unroll
    for (int i = 0; i < 256; ++i) m = m > umax[i] ? m : umax[i];
    return fmaxf(__uint_as_float(m) / 127.0f, 1e-8f);
}
// slots 1..5: 64 atomic buckets each at umax + 192 + 64*s
DI float get_sf(const unsigned* umax, int slot) {
    const unsigned* p = umax + 192 + slot * 64;
    unsigned m = 0u;
    #pragma unroll
    for (int i = 0; i < 64; ++i) m = m > p[i] ? m : p[i];
    return fmaxf(__uint_as_float(m) / 127.0f, 1e-8f);
}
DI void block_max_atomic(float v, unsigned* dst) {
    __shared__ float redm_[4];
    #pragma unroll
    for (int o = 32; o; o >>= 1) v = fmaxf(v, __shfl_down(v, o, 64));
    int wid = threadIdx.x >> 6;
    if ((threadIdx.x & 63) == 0) redm_[wid] = v;
    __syncthreads();
    if (threadIdx.x == 0) {
        int nw = blockDim.x >> 6;
        float m = redm_[0];
        for (int i = 1; i < nw; ++i) m = fmaxf(m, redm_[i]);
        atomicMax(dst + (blockIdx.x & 63), __float_as_uint(m));
    }
}

// ---------------- prep + absmax fused: grid 399 ----------------
// blocks 0..141 prep layers; 142 zero slots1-5; 143..398 absmax(x) plain-store
struct PrepEntry {
    const float *w, *g, *bb, *m, *v;
    float *wsf, *dst, *dst2, *bns, *bnb;
    int K; int has_bn; int mode;
};
struct PrepAll { PrepEntry e[6]; unsigned* umax; const float4* x; };

__global__ __launch_bounds__(256) void k_prep_all(PrepAll pa) {
    int blk = blockIdx.x;
    __shared__ float red[4];
    __shared__ float s_sf;
    if (blk >= 143) {                       // absmax: 256 blocks, plain store
        int j = blk - 143;
        float m = 0.f;
        for (int i = j * 256 + threadIdx.x; i < 786432; i += 65536) {
            float4 t = pa.x[i];
            m = fmaxf(m, fmaxf(fmaxf(fabsf(t.x), fabsf(t.y)), fmaxf(fabsf(t.z), fabsf(t.w))));
        }
        #pragma unroll
        for (int o = 32; o; o >>= 1) m = fmaxf(m, __shfl_down(m, o, 64));
        int wid = threadIdx.x >> 6;
        if ((threadIdx.x & 63) == 0) red[wid] = m;
        __syncthreads();
        if (threadIdx.x == 0)
            pa.umax[j] = __float_as_uint(fmaxf(fmaxf(red[0], red[1]), fmaxf(red[2], red[3])));
        return;
    }
    if (blk == 142) {
        for (int i = threadIdx.x; i < 320; i += 256) pa.umax[256 + i] = 0u;
        return;
    }
    int layer, oc;
    if      (blk < 32)  { layer = 0; oc = blk; }
    else if (blk < 36)  { layer = 1; oc = blk - 32; }
    else if (blk < 68)  { layer = 2; oc = blk - 36; }
    else if (blk < 100) { layer = 3; oc = blk - 68; }
    else if (blk < 132) { layer = 4; oc = blk - 100; }
    else                { layer = 5; oc = blk - 132; }
    PrepEntry a = pa.e[layer];
    const float* wr = a.w + (long)oc * a.K;
    float mx = 0.f;
    for (int i = threadIdx.x; i < a.K; i += 256) mx = fmaxf(mx, fabsf(wr[i]));
    #pragma unroll
    for (int o = 32; o; o >>= 1) mx = fmaxf(mx, __shfl_down(mx, o, 64));
    if ((threadIdx.x & 63) == 0) red[threadIdx.x >> 6] = mx;
    __syncthreads();
    if (threadIdx.x == 0) {
        float t = fmaxf(fmaxf(red[0], red[1]), fmaxf(red[2], red[3]));
        t = fmaxf(t / 127.0f, 1e-8f);
        a.wsf[oc] = t; s_sf = t;
        if (a.has_bn) {
            float inv = a.g[oc] / sqrtf(a.v[oc] + 1e-5f);
            a.bns[oc] = inv;
            a.bnb[oc] = a.bb[oc] - a.m[oc] * inv;
        }
    }
    __syncthreads();
    float sf = s_sf;
    for (int i = threadIdx.x; i < a.K; i += 256) {
        float q = rintf(wr[i] / sf);
        if (a.mode == 0) {
            a.dst[(long)oc * a.K + i] = q;
        } else if (a.mode == 1) {
            a.dst[i * 32 + oc] = q;
        } else if (a.mode == 2) {
            a.dst[i * 32 + oc] = q;
            a.dst2[oc * 28 + i] = q;
        } else {
            int ph = i / 72, kk = i - ph * 72;
            a.dst[ph * 2592 + kk * 36 + oc] = q;
        }
    }
    if (a.mode == 2 && threadIdx.x == 0) a.dst2[oc * 28 + 27] = 0.f;
}

// ---------------- conv0 pass 1: max only. grid 2048 = (image, row-half) ----------------
__global__ __launch_bounds__(256) void k_conv0maxN(
    const float* __restrict__ x, const float* __restrict__ w0kt,
    const float* __restrict__ wsf0, const float* __restrict__ bias0,
    const float* __restrict__ bns0, const float* __restrict__ bnb0,
    const unsigned* __restrict__ umax, unsigned* __restrict__ mout) {
    __shared__ float tile[3 * 18 * 36];
    __shared__ float wlds[27 * 32];
    __shared__ float As[32], Cs[32];
    const int b  = blockIdx.x >> 1;
    const int r0 = (blockIdx.x & 1) * 16;
    const int tid = threadIdx.x;
    const float sfx = get_sf0(umax);
    const float rsfx = 1.0f / sfx;
    if (tid < 32) {
        int oc = tid;
        float bsf = wsf0[oc] * sfx;
        float bint = rintf(bias0[oc] / bsf);
        float a = bsf * bns0[oc];
        As[oc] = a;
        Cs[oc] = fmaf(bint, a, bnb0[oc]);
    }
    for (int i = tid; i < 1944; i += 256) tile[i] = 0.f;
    if (tid < 216) ((float4*)wlds)[tid] = ((const float4*)w0kt)[tid];
    __syncthreads();
    const float* xb = x + (long)b * 3072;
    for (int i = tid; i < 1728; i += 256) {
        int ci = i / 576, rem = i - ci * 576;
        int rr = rem >> 5, cc = rem & 31;
        int gr = r0 - 1 + rr;
        if ((unsigned)gr < 32u)
            tile[ci * 648 + rr * 36 + cc + 1] = quantm(xb[ci * 1024 + gr * 32 + cc], rsfx);
    }
    __syncthreads();
    const int oc0  = (tid >> 5) * 4;
    const int pxg  = tid & 31;
    const int row  = pxg >> 1;
    const int wcol = (pxg & 1) * 16;
    float acc[4][16];
    #pragma unroll
    for (int o = 0; o < 4; ++o)
        #pragma unroll
        for (int p = 0; p < 16; ++p) acc[o][p] = 0.f;
    #pragma unroll
    for (int kk = 0; kk < 9; ++kk) {
        int ci = kk / 3, ky = kk - ci * 3;
        const float* rp = tile + ci * 648 + (row + ky) * 36 + wcol;
        float wn[20];
        #pragma unroll
        for (int d = 0; d < 5; ++d) *(float4*)&wn[4 * d] = *(const float4*)&rp[4 * d];
        #pragma unroll
        for (int kx = 0; kx < 3; ++kx) {
            float4 wv = *(const float4*)&wlds[(kk * 3 + kx) * 32 + oc0];
            const float* wf = &wv.x;
            #pragma unroll
            for (int o = 0; o < 4; ++o)
                #pragma unroll
                for (int p = 0; p < 16; ++p)
                    acc[o][p] = fmaf(wn[p + kx], wf[o], acc[o][p]);
        }
    }
    float lmax = 0.f;
    #pragma unroll
    for (int o = 0; o < 4; ++o) {
        float A = As[oc0 + o], C = Cs[oc0 + o];
        #pragma unroll
        for (int p = 0; p < 16; ++p)
            lmax = fmaxf(lmax, fabsf(fmaf(acc[o][p], A, C)));
    }
    block_max_atomic(lmax, mout);
}

// ---------------- conv0 pass 2 + fused 1x1 conv1. grid 1024 ----------------
__global__ __launch_bounds__(256) void k_conv01n(
    const float* __restrict__ x, const float* __restrict__ w0p,
    const float* __restrict__ wsf0, const float* __restrict__ bias0,
    const float* __restrict__ bns0, const float* __restrict__ bnb0,
    const float* __restrict__ w1i,
    const float* __restrict__ wsf1, const float* __restrict__ bias1,
    const float* __restrict__ bns1, const float* __restrict__ bnb1,
    const unsigned* __restrict__ umax, unsigned* __restrict__ mout,
    float* __restrict__ out) {
    __shared__ float tile[3672];
    __shared__ float wls0[896];
    __shared__ float wls1[128];
    __shared__ float Aq[32], Cq[32];
    __shared__ float A1s[4], C1s[4];
    const int b   = blockIdx.x;
    const int tid = threadIdx.x;
    const float sfx = get_sf0(umax);
    const float rsfx = 1.0f / sfx;
    const float sf1 = get_sf(umax, 1);
    const float rsf1 = 1.0f / sf1;
    if (tid < 32) {
        int oc = tid;
        float bsf = wsf0[oc] * sfx;
        float bint = rintf(bias0[oc] / bsf);
        float a = bsf * bns0[oc];
        float c = fmaf(bint, a, bnb0[oc]);
        Aq[oc] = a * rsf1;
        Cq[oc] = c * rsf1;
    }
    if (tid >= 64 && tid < 68) {
        int oc = tid - 64;
        float bsf = wsf1[oc] * sf1;
        float bint = rintf(bias1[oc] / bsf);
        float a = bsf * bns1[oc];
        A1s[oc] = a;
        C1s[oc] = fmaf(bint, a, bnb1[oc]);
    }
    for (int i = tid; i < 3672; i += 256) tile[i] = 0.f;
    if (tid < 224) ((float4*)wls0)[tid] = ((const float4*)w0p)[tid];
    if (tid >= 128 && tid < 256) {
        int j = tid - 128;
        wls1[(j & 31) * 4 + (j >> 5)] = w1i[j];
    }
    __syncthreads();
    const float* xb = x + (long)b * 3072;
    for (int i = tid; i < 3072; i += 256) {
        int ci = i >> 10, px = i & 1023;
        int iy = px >> 5, ix = px & 31;
        tile[ci * 1224 + (iy + 1) * 36 + (ix + 1)] = quantm(xb[i], rsfx);
    }
    __syncthreads();
    const int h   = tid >> 3;
    const int w0c = (tid & 7) * 4;
    float win[3][3][6];
    #pragma unroll
    for (int ci = 0; ci < 3; ++ci)
        #pragma unroll
        for (int ky = 0; ky < 3; ++ky) {
            const int base = ci * 1224 + (h + ky) * 36 + w0c;
            *(float4*)&win[ci][ky][0] = *(const float4*)&tile[base];
            *(float2*)&win[ci][ky][4] = *(const float2*)&tile[base + 4];
        }
    float acc1[4][4];
    #pragma unroll
    for (int o = 0; o < 4; ++o)
        #pragma unroll
        for (int p = 0; p < 4; ++p) acc1[o][p] = 0.f;
    #pragma unroll 2
    for (int oc = 0; oc < 32; ++oc) {
        float wreg[28];
        const float4* wp4 = (const float4*)&wls0[oc * 28];
        #pragma unroll
        for (int d = 0; d < 7; ++d) *(float4*)&wreg[4 * d] = wp4[d];
        float a0 = 0.f, a1 = 0.f, a2 = 0.f, a3 = 0.f;
        #pragma unroll
        for (int ci = 0; ci < 3; ++ci)
            #pragma unroll
            for (int ky = 0; ky < 3; ++ky)
                #pragma unroll
                for (int kx = 0; kx < 3; ++kx) {
                    float wv = wreg[ci * 9 + ky * 3 + kx];
                    a0 = fmaf(win[ci][ky][kx + 0], wv, a0);
                    a1 = fmaf(win[ci][ky][kx + 1], wv, a1);
                    a2 = fmaf(win[ci][ky][kx + 2], wv, a2);
                    a3 = fmaf(win[ci][ky][kx + 3], wv, a3);
                }
        float A = Aq[oc], C = Cq[oc];
        float q0 = fminf(fmaxf(rintf(fmaf(a0, A, C)), -127.0f), 127.0f);
        float q1 = fminf(fmaxf(rintf(fmaf(a1, A, C)), -127.0f), 127.0f);
        float q2 = fminf(fmaxf(rintf(fmaf(a2, A, C)), -127.0f), 127.0f);
        float q3 = fminf(fmaxf(rintf(fmaf(a3, A, C)), -127.0f), 127.0f);
        const float4 w1v = *(const float4*)&wls1[oc * 4];
        acc1[0][0] = fmaf(q0, w1v.x, acc1[0][0]); acc1[0][1] = fmaf(q1, w1v.x, acc1[0][1]);
        acc1[0][2] = fmaf(q2, w1v.x, acc1[0][2]); acc1[0][3] = fmaf(q3, w1v.x, acc1[0][3]);
        acc1[1][0] = fmaf(q0, w1v.y, acc1[1][0]); acc1[1][1] = fmaf(q1, w1v.y, acc1[1][1]);
        acc1[1][2] = fmaf(q2, w1v.y, acc1[1][2]); acc1[1][3] = fmaf(q3, w1v.y, acc1[1][3]);
        acc1[2][0] = fmaf(q0, w1v.z, acc1[2][0]); acc1[2][1] = fmaf(q1, w1v.z, acc1[2][1]);
        acc1[2][2] = fmaf(q2, w1v.z, acc1[2][2]); acc1[2][3] = fmaf(q3, w1v.z, acc1[2][3]);
        acc1[3][0] = fmaf(q0, w1v.w, acc1[3][0]); acc1[3][1] = fmaf(q1, w1v.w, acc1[3][1]);
        acc1[3][2] = fmaf(q2, w1v.w, acc1[3][2]); acc1[3][3] = fmaf(q3, w1v.w, acc1[3][3]);
    }
    float lmax = 0.f;
    float* ob = out + (long)b * 4096 + h * 32 + w0c;
    #pragma unroll
    for (int o = 0; o < 4; ++o) {
        float y0 = fmaf(acc1[o][0], A1s[o], C1s[o]);
        float y1 = fmaf(acc1[o][1], A1s[o], C1s[o]);
        float y2 = fmaf(acc1[o][2], A1s[o], C1s[o]);
        float y3 = fmaf(acc1[o][3], A1s[o], C1s[o]);
        lmax = fmaxf(lmax, fmaxf(fmaxf(fabsf(y0), fabsf(y1)), fmaxf(fabsf(y2), fabsf(y3))));
        float4 r4; r4.x = y0; r4.y = y1; r4.z = y2; r4.w = y3;
        *(float4*)&ob[o * 1024] = r4;
    }
    block_max_atomic(lmax, mout);
}

// ---------------- conv2 (4->32, 3x3, s2): thread = 8 oc x 4 px ----------------
__global__ __launch_bounds__(256) void k_conv2c(
    const float* __restrict__ inp, const float* __restrict__ w2kt,
    const float* __restrict__ wsf, const float* __restrict__ bias,
    const float* __restrict__ bns, const float* __restrict__ bnb,
    const unsigned* __restrict__ umax, unsigned* __restrict__ mout,
    float* __restrict__ out) {
    __shared__ float tile[4 * 34 * 36];
    __shared__ float wlds[36 * 32];
    __shared__ float As[32], Cs[32];
    const int tid = threadIdx.x;
    const float sf = get_sf(umax, 2);
    const float rsf = 1.0f / sf;
    if (tid < 32) {
        int oc = tid;
        float bsf = wsf[oc] * sf;
        float bint = rintf(bias[oc] / bsf);
        float a = bsf * bns[oc];
        As[oc] = a;
        Cs[oc] = fmaf(bint, a, bnb[oc]);
    }
    for (int i = tid; i < 4896; i += 256) tile[i] = 0.f;
    for (int i = tid; i < 288; i += 256) ((float4*)wlds)[i] = ((const float4*)w2kt)[i];
    __syncthreads();
    const float* ib = inp + (long)blockIdx.x * 4096;
    for (int i = tid; i < 4096; i += 256) {
        int ci = i >> 10, px = i & 1023;
        int iy = px >> 5, ix = px & 31;
        tile[ci * 1224 + (iy + 1) * 36 + (ix + 1)] = quantm(ib[i], rsf);
    }
    __syncthreads();
    const int oc0 = (tid >> 6) * 8;
    const int pxq = tid & 63;
    const int h = pxq >> 2, c = pxq & 3;
    float acc[8][4];
    #pragma unroll
    for (int k = 0; k < 8; ++k)
        #pragma unroll
        for (int p = 0; p < 4; ++p) acc[k][p] = 0.f;
    #pragma unroll
    for (int ci = 0; ci < 4; ++ci) {
        #pragma unroll
        for (int ky = 0; ky < 3; ++ky) {
            const float* rp = tile + ci * 1224 + (2 * h + ky) * 36 + 8 * c;
            float wn[12];
            #pragma unroll
            for (int d = 0; d < 3; ++d) *(float4*)&wn[4 * d] = *(const float4*)&rp[4 * d];
            #pragma unroll
            for (int kx = 0; kx < 3; ++kx) {
                const float* wp = &wlds[(ci * 9 + ky * 3 + kx) * 32 + oc0];
                float4 wa = *(const float4*)&wp[0];
                float4 wb = *(const float4*)&wp[4];
                float wf[8] = {wa.x, wa.y, wa.z, wa.w, wb.x, wb.y, wb.z, wb.w};
                #pragma unroll
                for (int k = 0; k < 8; ++k)
                    #pragma unroll
                    for (int p = 0; p < 4; ++p)
                        acc[k][p] = fmaf(wn[2 * p + kx], wf[k], acc[k][p]);
            }
        }
    }
    float lmax = 0.f;
    float* ob = out + (long)blockIdx.x * 8192;
    #pragma unroll
    for (int k = 0; k < 8; ++k) {
        int oc = oc0 + k;
        float A = As[oc], C = Cs[oc];
        float4 r;
        float* rp = &r.x;
        #pragma unroll
        for (int p = 0; p < 4; ++p) {
            float y = fmaf(acc[k][p], A, C);
            rp[p] = y;
            lmax = fmaxf(lmax, fabsf(y));
        }
        *(float4*)&ob[oc * 256 + h * 16 + c * 4] = r;
    }
    block_max_atomic(lmax, mout);
}

// ---------------- conv3/conv4: 2 img/block(128 thr), thread = 4oc x 2row x 4col ----------------
template<int HIN, int S>
__global__ __launch_bounds__(128) void k_conv34e(
    const float* __restrict__ inp, const float* __restrict__ wt,
    const float* __restrict__ wsf, const float* __restrict__ bias,
    const float* __restrict__ bns, const float* __restrict__ bnb,
    const unsigned* __restrict__ umax, int slot, unsigned* __restrict__ mout,
    float* __restrict__ out) {
    constexpr int ROWS = HIN + 2;
    constexpr int RS   = (S == 2) ? 20 : 12;
    constexpr int TI   = 8 * ROWS * RS;
    constexpr int PIX  = HIN * HIN;
    constexpr int PSH  = (HIN == 16) ? 8 : 6;
    constexpr int HSH  = (HIN == 16) ? 4 : 3;
    constexpr int NELT = 2 * 8 * PIX;
    constexpr int NR   = S + 3;                 // window rows (5 or 4)
    constexpr int NCF  = (S == 2) ? 3 : 2;      // f4 per window row
    __shared__ float tile[2 * TI];
    __shared__ float wlds[2592];
    __shared__ float As[32], Cs[32];
    const int tid  = threadIdx.x;               // 0..127
    const int imgl = tid >> 6;
    const int ocg  = (tid >> 3) & 7;
    const int pxq  = tid & 7;
    const int h2 = pxq >> 1, c = pxq & 1;       // out rows 2h2,2h2+1; cols 4c..4c+3
    const float sf = get_sf(umax, slot);
    const float rsf = 1.0f / sf;
    if (tid < 32) {
        int oc = tid;
        float bsf = wsf[oc] * sf;
        float bint = rintf(bias[oc] / bsf);
        float a = bsf * bns[oc];
        As[oc] = a;
        Cs[oc] = fmaf(bint, a, bnb[oc]);
    }
    for (int i = tid; i < 2 * TI; i += 128) tile[i] = 0.f;
    float acc[4][2][4];
    #pragma unroll
    for (int k = 0; k < 4; ++k)
        #pragma unroll
        for (int r = 0; r < 2; ++r)
            #pragma unroll
            for (int p = 0; p < 4; ++p) acc[k][r][p] = 0.f;
    const float* ib = inp + (long)blockIdx.x * 2 * 32 * PIX;
    const float4* wt4 = (const float4*)wt;
    for (int ph = 0; ph < 4; ++ph) {
        __syncthreads();
        for (int i = tid; i < NELT; i += 128) {
            int im = i >> (PSH + 3);
            int ci = (i >> PSH) & 7;
            int px = i & (PIX - 1);
            int iy = px >> HSH, ix = px & (HIN - 1);
            tile[im * TI + ci * (ROWS * RS) + (iy + 1) * RS + (ix + 1)] =
                quantm(ib[(long)((im * 32 + ph * 8 + ci) << PSH) + px], rsf);
        }
        for (int i = tid; i < 648; i += 128) ((float4*)wlds)[i] = wt4[ph * 648 + i];
        __syncthreads();
        const int tbo = imgl * TI;
        #pragma unroll
        for (int ci = 0; ci < 8; ++ci) {
            float win[NR][NCF * 4];
            #pragma unroll
            for (int rr = 0; rr < NR; ++rr) {
                const int base = tbo + ci * (ROWS * RS) + (2 * S * h2 + rr) * RS + S * 4 * c;
                #pragma unroll
                for (int d = 0; d < NCF; ++d)
                    *(float4*)&win[rr][4 * d] = *(const float4*)&tile[base + 4 * d];
            }
            #pragma unroll
            for (int ky = 0; ky < 3; ++ky)
                #pragma unroll
                for (int kx = 0; kx < 3; ++kx) {
                    float4 wv = *(const float4*)&wlds[(ci * 9 + ky * 3 + kx) * 36 + ocg * 4];
                    float x00 = win[ky][S * 0 + kx];
                    float x01 = win[ky][S * 1 + kx];
                    float x02 = win[ky][S * 2 + kx];
                    float x03 = win[ky][S * 3 + kx];
                    float x10 = win[S + ky][S * 0 + kx];
                    float x11 = win[S + ky][S * 1 + kx];
                    float x12 = win[S + ky][S * 2 + kx];
                    float x13 = win[S + ky][S * 3 + kx];
                    acc[0][0][0] = fmaf(x00, wv.x, acc[0][0][0]); acc[0][0][1] = fmaf(x01, wv.x, acc[0][0][1]);
                    acc[0][0][2] = fmaf(x02, wv.x, acc[0][0][2]); acc[0][0][3] = fmaf(x03, wv.x, acc[0][0][3]);
                    acc[0][1][0] = fmaf(x10, wv.x, acc[0][1][0]); acc[0][1][1] = fmaf(x11, wv.x, acc[0][1][1]);
                    acc[0][1][2] = fmaf(x12, wv.x, acc[0][1][2]); acc[0][1][3] = fmaf(x13, wv.x, acc[0][1][3]);
                    acc[1][0][0] = fmaf(x00, wv.y, acc[1][0][0]); acc[1][0][1] = fmaf(x01, wv.y, acc[1][0][1]);
                    acc[1][0][2] = fmaf(x02, wv.y, acc[1][0][2]); acc[1][0][3] = fmaf(x03, wv.y, acc[1][0][3]);
                    acc[1][1][0] = fmaf(x10, wv.y, acc[1][1][0]); acc[1][1][1] = fmaf(x11, wv.y, acc[1][1][1]);
                    acc[1][1][2] = fmaf(x12, wv.y, acc[1][1][2]); acc[1][1][3] = fmaf(x13, wv.y, acc[1][1][3]);
                    acc[2][0][0] = fmaf(x00, wv.z, acc[2][0][0]); acc[2][0][1] = fmaf(x01, wv.z, acc[2][0][1]);
                    acc[2][0][2] = fmaf(x02, wv.z, acc[2][0][2]); acc[2][0][3] = fmaf(x03, wv.z, acc[2][0][3]);
                    acc[2][1][0] = fmaf(x10, wv.z, acc[2][1][0]); acc[2][1][1] = fmaf(x11, wv.z, acc[2][1][1]);
                    acc[2][1][2] = fmaf(x12, wv.z, acc[2][1][2]); acc[2][1][3] = fmaf(x13, wv.z, acc[2][1][3]);
                    acc[3][0][0] = fmaf(x00, wv.w, acc[3][0][0]); acc[3][0][1] = fmaf(x01, wv.w, acc[3][0][1]);
                    acc[3][0][2] = fmaf(x02, wv.w, acc[3][0][2]); acc[3][0][3] = fmaf(x03, wv.w, acc[3][0][3]);
                    acc[3][1][0] = fmaf(x10, wv.w, acc[3][1][0]); acc[3][1][1] = fmaf(x11, wv.w, acc[3][1][1]);
                    acc[3][1][2] = fmaf(x12, wv.w, acc[3][1][2]); acc[3][1][3] = fmaf(x13, wv.w, acc[3][1][3]);
                }
        }
    }
    float lmax = 0.f;
    long imgg = (long)blockIdx.x * 2 + imgl;
    #pragma unroll
    for (int k = 0; k < 4; ++k) {
        int oc = ocg * 4 + k;
        float A = As[oc], C = Cs[oc];
        #pragma unroll
        for (int r = 0; r < 2; ++r) {
            float y0 = fmaf(acc[k][r][0], A, C);
            float y1 = fmaf(acc[k][r][1], A, C);
            float y2 = fmaf(acc[k][r][2], A, C);
            float y3 = fmaf(acc[k][r][3], A, C);
            lmax = fmaxf(lmax, fmaxf(fmaxf(fabsf(y0), fabsf(y1)), fmaxf(fabsf(y2), fabsf(y3))));
            float4 r4; r4.x = y0; r4.y = y1; r4.z = y2; r4.w = y3;
            *(float4*)&out[(imgg * 32 + oc) * 64 + (2 * h2 + r) * 8 + c * 4] = r4;
        }
    }
    block_max_atomic(lmax, mout);
}

// ---------------- linear 2048->10 per image ----------------
__global__ __launch_bounds__(256) void k_fc(
    const float* __restrict__ act, const float* __restrict__ wdi,
    const float* __restrict__ wsfd, const float* __restrict__ bd,
    const unsigned* __restrict__ umax, float* __restrict__ logits) {
    int b = blockIdx.x;
    float sf = get_sf(umax, 5);
    float rsf = 1.0f / sf;
    const float* ab = act + (long)b * 2048;
    float acc[10];
    #pragma unroll
    for (int c = 0; c < 10; ++c) acc[c] = 0.f;
    #pragma unroll
    for (int k = 0; k < 8; ++k) {
        int j = threadIdx.x + 256 * k;
        float q = quantm(ab[j], rsf);
        #pragma unroll
        for (int c = 0; c < 10; ++c) acc[c] = fmaf(q, wdi[c * 2048 + j], acc[c]);
    }
    #pragma unroll
    for (int c = 0; c < 10; ++c)
        #pragma unroll
        for (int o = 32; o; o >>= 1) acc[c] += __shfl_down(acc[c], o, 64);
    __shared__ float red[4][10];
    int wid = threadIdx.x >> 6;
    if ((threadIdx.x & 63) == 0)
        #pragma unroll
        for (int c = 0; c < 10; ++c) red[wid][c] = acc[c];
    __syncthreads();
    if (threadIdx.x < 10) {
        int c = threadIdx.x;
        float s = red[0][c] + red[1][c] + red[2][c] + red[3][c];
        float bsf = wsfd[c] * sf;
        float bint = rintf(bd[c] / bsf);
        logits[b * 10 + c] = (s + bint) * bsf;
    }
}

// ---------------- softmax over batch axis (dim 0) ----------------
__global__ __launch_bounds__(256) void k_softmax(const float* __restrict__ logits, float* __restrict__ out) {
    int c = blockIdx.x;
    float v0 = logits[(threadIdx.x +   0) * 10 + c];
    float v1 = logits[(threadIdx.x + 256) * 10 + c];
    float v2 = logits[(threadIdx.x + 512) * 10 + c];
    float v3 = logits[(threadIdx.x + 768) * 10 + c];
    float mx = fmaxf(fmaxf(v0, v1), fmaxf(v2, v3));
    __shared__ float redm[4];
    __shared__ float reds[4];
    #pragma unroll
    for (int o = 32; o; o >>= 1) mx = fmaxf(mx, __shfl_down(mx, o, 64));
    if ((threadIdx.x & 63) == 0) redm[threadIdx.x >> 6] = mx;
    __syncthreads();
    mx = fmaxf(fmaxf(redm[0], redm[1]), fmaxf(redm[2], redm[3]));
    float e0 = expf(v0 - mx), e1 = expf(v1 - mx), e2 = expf(v2 - mx), e3 = expf(v3 - mx);
    float s = (e0 + e1) + (e2 + e3);
    #pragma unroll
    for (int o = 32; o; o >>= 1) s += __shfl_down(s, o, 64);
    if ((threadIdx.x & 63) == 0) reds[threadIdx.x >> 6] = s;
    __syncthreads();
    s = reds[0] + reds[1] + reds[2] + reds[3];
    out[(threadIdx.x +   0) * 10 + c] = e0 / s;
    out[(threadIdx.x + 256) * 10 + c] = e1 / s;
    out[(threadIdx.x + 512) * 10 + c] = e2 / s;
    out[(threadIdx.x + 768) * 10 + c] = e3 / s;
}

extern "C" void kernel_launch(void* const* d_in, const int* in_sizes, int n_in,
                              void* d_out, int out_size, void* d_ws, size_t ws_size,
                              hipStream_t stream) {
    (void)in_sizes; (void)n_in; (void)out_size; (void)ws_size;
    const float* x = (const float*)d_in[0];
    const float *w[5], *bia[5], *g[5], *bb[5], *m[5], *v[5];
    for (int i = 0; i < 5; ++i) {
        w[i]   = (const float*)d_in[1 + 6 * i + 0];
        bia[i] = (const float*)d_in[1 + 6 * i + 1];
        g[i]   = (const float*)d_in[1 + 6 * i + 2];
        bb[i]  = (const float*)d_in[1 + 6 * i + 3];
        m[i]   = (const float*)d_in[1 + 6 * i + 4];
        v[i]   = (const float*)d_in[1 + 6 * i + 5];
    }
    const float* wd = (const float*)d_in[31];
    const float* bd = (const float*)d_in[32];
    float* ws = (float*)d_ws;
    unsigned* umax = (unsigned*)ws;   // [256] slot0 + [5][64] slots1-5
    float* out = (float*)d_out;

    float* w0kt = ws + OFF_W0KT;
    float* w0p  = ws + OFF_W0P;
    float* w1i  = ws + OFF_W1I;
    float* w2kt = ws + OFF_W2KT;
    float* w3t  = ws + OFF_W3T;
    float* w4t  = ws + OFF_W4T;
    float* wdi  = ws + OFF_WDI;
    float* wsf0 = ws + OFF_WSF0; float* bns0 = ws + OFF_BNS0; float* bnb0 = ws + OFF_BNB0;
    float* wsf1 = ws + OFF_WSF1; float* bns1 = ws + OFF_BNS1; float* bnb1 = ws + OFF_BNB1;
    float* wsf2 = ws + OFF_WSF2; float* bns2 = ws + OFF_BNS2; float* bnb2 = ws + OFF_BNB2;
    float* wsf3 = ws + OFF_WSF3; float* bns3 = ws + OFF_BNS3; float* bnb3 = ws + OFF_BNB3;
    float* wsf4 = ws + OFF_WSF4; float* bns4 = ws + OFF_BNS4; float* bnb4 = ws + OFF_BNB4;
    float* wsfd = ws + OFF_WSFD;
    float* logits = ws + OFF_LOG;
    float* actA = ws + ACT_A_OFF;   // act2 / act4
    float* actB = ws + ACT_B_OFF;   // act1 / act3

    PrepAll pa;
    pa.umax = umax;
    pa.x = (const float4*)x;
    const float* ww[6] = {w[0], w[1], w[2], w[3], w[4], wd};
    float* wsfp[6] = {wsf0, wsf1, wsf2, wsf3, wsf4, wsfd};
    float* dstp[6] = {w0kt, w1i, w2kt, w3t, w4t, wdi};
    float* dst2p[6] = {w0p, nullptr, nullptr, nullptr, nullptr, nullptr};
    float* bnsp[6] = {bns0, bns1, bns2, bns3, bns4, nullptr};
    float* bnbp[6] = {bnb0, bnb1, bnb2, bnb3, bnb4, nullptr};
    int Ks[6]   = {27, 32, 36, 288, 288, 2048};
    int modes[6] = {2, 0, 1, 3, 3, 0};
    for (int i = 0; i < 6; ++i) {
        pa.e[i].w = ww[i];
        pa.e[i].g = (i < 5) ? g[i] : nullptr;
        pa.e[i].bb = (i < 5) ? bb[i] : nullptr;
        pa.e[i].m = (i < 5) ? m[i] : nullptr;
        pa.e[i].v = (i < 5) ? v[i] : nullptr;
        pa.e[i].wsf = wsfp[i];
        pa.e[i].dst = dstp[i];
        pa.e[i].dst2 = dst2p[i];
        pa.e[i].bns = bnsp[i];
        pa.e[i].bnb = bnbp[i];
        pa.e[i].K = Ks[i];
        pa.e[i].has_bn = (i < 5) ? 1 : 0;
        pa.e[i].mode = modes[i];
    }

    hipLaunchKernelGGL(k_prep_all, dim3(399), dim3(256), 0, stream, pa);
    hipLaunchKernelGGL(k_conv0maxN, dim3(2048), dim3(256), 0, stream,
                       x, w0kt, wsf0, bia[0], bns0, bnb0, umax, umax + 256);
    hipLaunchKernelGGL(k_conv01n, dim3(1024), dim3(256), 0, stream,
                       x, w0p, wsf0, bia[0], bns0, bnb0,
                       w1i, wsf1, bia[1], bns1, bnb1, umax, umax + 320, actB);
    hipLaunchKernelGGL(k_conv2c, dim3(1024), dim3(256), 0, stream,
                       actB, w2kt, wsf2, bia[2], bns2, bnb2, umax, umax + 384, actA);
    hipLaunchKernelGGL((k_conv34e<16, 2>), dim3(512), dim3(128), 0, stream,
                       actA, w3t, wsf3, bia[3], bns3, bnb3, umax, 3, umax + 448, actB);
    hipLaunchKernelGGL((k_conv34e<8, 1>),  dim3(512), dim3(128), 0, stream,
                       actB, w4t, wsf4, bia[4], bns4, bnb4, umax, 4, umax + 512, actA);
    hipLaunchKernelGGL(k_fc, dim3(1024), dim3(256), 0, stream, actA, wdi, wsfd, bd, umax, logits);
    hipLaunchKernelGGL(k_softmax, dim3(10), dim3(256), 0, stream, logits, out);
}

// Round 19
// 159.878 us; speedup vs baseline: 1.1175x; 1.1175x over previous
//
#include <hip/hip_runtime.h>

#define DI __device__ __forceinline__

// ---------------- ws layout (float offsets) ----------------
// umax: [0..255] slot0 plain-store buckets (|x|), [256..575] slots1-5 atomic buckets (64 each)
constexpr int OFF_W0KT = 576;     // 27*32 (k-major, conv0maxN)
constexpr int OFF_W0P  = 1440;    // 32*28 (padded oc-major, conv01n)
constexpr int OFF_W1I  = 2336;    // 4*32
constexpr int OFF_W2KT = 2464;    // 36*32 (k-major, conv2c)
constexpr int OFF_W3T  = 3616;    // 4*72*36 (phase-k-major, conv3)
constexpr int OFF_W4T  = 13984;   // 10368
constexpr int OFF_WDI  = 24352;   // 20480
constexpr int OFF_WSF0 = 44832;
constexpr int OFF_BNS0 = 44864;
constexpr int OFF_BNB0 = 44896;
constexpr int OFF_WSF1 = 44928;
constexpr int OFF_BNS1 = 44932;
constexpr int OFF_BNB1 = 44936;
constexpr int OFF_WSF2 = 44940;
constexpr int OFF_BNS2 = 44972;
constexpr int OFF_BNB2 = 45004;
constexpr int OFF_WSF3 = 45036;
constexpr int OFF_BNS3 = 45068;
constexpr int OFF_BNB3 = 45100;
constexpr int OFF_WSF4 = 45132;
constexpr int OFF_BNS4 = 45164;
constexpr int OFF_BNB4 = 45196;
constexpr int OFF_WSFD = 45228;   // 10
constexpr int OFF_LOG  = 45248;   // 10240
constexpr int OFF_ACT  = 55488;
constexpr long ACT_A_OFF = OFF_ACT;              // act2/act4
constexpr long ACT_B_OFF = OFF_ACT + 8388608L;   // act1/act3

// ---------------- helpers ----------------
DI float quantm(float x, float rsf) {
    float q = rintf(x * rsf);
    return fminf(fmaxf(q, -127.0f), 127.0f);
}
// slot 0: 256 plain-stored buckets
DI float get_sf0(const unsigned* umax) {
    unsigned m = 0u;
    #pragma unroll
    for (int i = 0; i < 256; ++i) m = m > umax[i] ? m : umax[i];
    return fmaxf(__uint_as_float(m) / 127.0f, 1e-8f);
}
// slots 1..5: 64 atomic buckets each at umax + 192 + 64*s
DI float get_sf(const unsigned* umax, int slot) {
    const unsigned* p = umax + 192 + slot * 64;
    unsigned m = 0u;
    #pragma unroll
    for (int i = 0; i < 64; ++i) m = m > p[i] ? m : p[i];
    return fmaxf(__uint_as_float(m) / 127.0f, 1e-8f);
}
DI void block_max_atomic(float v, unsigned* dst) {
    __shared__ float redm_[4];
    #pragma unroll
    for (int o = 32; o; o >>= 1) v = fmaxf(v, __shfl_down(v, o, 64));
    int wid = threadIdx.x >> 6;
    if ((threadIdx.x & 63) == 0) redm_[wid] = v;
    __syncthreads();
    if (threadIdx.x == 0) {
        int nw = blockDim.x >> 6;
        float m = redm_[0];
        for (int i = 1; i < nw; ++i) m = fmaxf(m, redm_[i]);
        atomicMax(dst + (blockIdx.x & 63), __float_as_uint(m));
    }
}

// ---------------- prep + absmax fused: grid 399 ----------------
struct PrepEntry {
    const float *w, *g, *bb, *m, *v;
    float *wsf, *dst, *dst2, *bns, *bnb;
    int K; int has_bn; int mode;
};
struct PrepAll { PrepEntry e[6]; unsigned* umax; const float4* x; };

__global__ __launch_bounds__(256) void k_prep_all(PrepAll pa) {
    int blk = blockIdx.x;
    __shared__ float red[4];
    __shared__ float s_sf;
    if (blk >= 143) {                       // absmax: 256 blocks, plain store
        int j = blk - 143;
        float m = 0.f;
        for (int i = j * 256 + threadIdx.x; i < 786432; i += 65536) {
            float4 t = pa.x[i];
            m = fmaxf(m, fmaxf(fmaxf(fabsf(t.x), fabsf(t.y)), fmaxf(fabsf(t.z), fabsf(t.w))));
        }
        #pragma unroll
        for (int o = 32; o; o >>= 1) m = fmaxf(m, __shfl_down(m, o, 64));
        int wid = threadIdx.x >> 6;
        if ((threadIdx.x & 63) == 0) red[wid] = m;
        __syncthreads();
        if (threadIdx.x == 0)
            pa.umax[j] = __float_as_uint(fmaxf(fmaxf(red[0], red[1]), fmaxf(red[2], red[3])));
        return;
    }
    if (blk == 142) {
        for (int i = threadIdx.x; i < 320; i += 256) pa.umax[256 + i] = 0u;
        return;
    }
    int layer, oc;
    if      (blk < 32)  { layer = 0; oc = blk; }
    else if (blk < 36)  { layer = 1; oc = blk - 32; }
    else if (blk < 68)  { layer = 2; oc = blk - 36; }
    else if (blk < 100) { layer = 3; oc = blk - 68; }
    else if (blk < 132) { layer = 4; oc = blk - 100; }
    else                { layer = 5; oc = blk - 132; }
    PrepEntry a = pa.e[layer];
    const float* wr = a.w + (long)oc * a.K;
    float mx = 0.f;
    for (int i = threadIdx.x; i < a.K; i += 256) mx = fmaxf(mx, fabsf(wr[i]));
    #pragma unroll
    for (int o = 32; o; o >>= 1) mx = fmaxf(mx, __shfl_down(mx, o, 64));
    if ((threadIdx.x & 63) == 0) red[threadIdx.x >> 6] = mx;
    __syncthreads();
    if (threadIdx.x == 0) {
        float t = fmaxf(fmaxf(red[0], red[1]), fmaxf(red[2], red[3]));
        t = fmaxf(t / 127.0f, 1e-8f);
        a.wsf[oc] = t; s_sf = t;
        if (a.has_bn) {
            float inv = a.g[oc] / sqrtf(a.v[oc] + 1e-5f);
            a.bns[oc] = inv;
            a.bnb[oc] = a.bb[oc] - a.m[oc] * inv;
        }
    }
    __syncthreads();
    float sf = s_sf;
    for (int i = threadIdx.x; i < a.K; i += 256) {
        float q = rintf(wr[i] / sf);
        if (a.mode == 0) {
            a.dst[(long)oc * a.K + i] = q;
        } else if (a.mode == 1) {
            a.dst[i * 32 + oc] = q;
        } else if (a.mode == 2) {
            a.dst[i * 32 + oc] = q;
            a.dst2[oc * 28 + i] = q;
        } else {
            int ph = i / 72, kk = i - ph * 72;
            a.dst[ph * 2592 + kk * 36 + oc] = q;
        }
    }
    if (a.mode == 2 && threadIdx.x == 0) a.dst2[oc * 28 + 27] = 0.f;
}

// ---------------- conv0 pass 1: max only. grid 2048 = (image, row-half) ----------------
__global__ __launch_bounds__(256) void k_conv0maxN(
    const float* __restrict__ x, const float* __restrict__ w0kt,
    const float* __restrict__ wsf0, const float* __restrict__ bias0,
    const float* __restrict__ bns0, const float* __restrict__ bnb0,
    const unsigned* __restrict__ umax, unsigned* __restrict__ mout) {
    __shared__ float tile[3 * 18 * 36];
    __shared__ float wlds[27 * 32];
    __shared__ float As[32], Cs[32];
    const int b  = blockIdx.x >> 1;
    const int r0 = (blockIdx.x & 1) * 16;
    const int tid = threadIdx.x;
    const float sfx = get_sf0(umax);
    const float rsfx = 1.0f / sfx;
    if (tid < 32) {
        int oc = tid;
        float bsf = wsf0[oc] * sfx;
        float bint = rintf(bias0[oc] / bsf);
        float a = bsf * bns0[oc];
        As[oc] = a;
        Cs[oc] = fmaf(bint, a, bnb0[oc]);
    }
    for (int i = tid; i < 1944; i += 256) tile[i] = 0.f;
    if (tid < 216) ((float4*)wlds)[tid] = ((const float4*)w0kt)[tid];
    __syncthreads();
    const float* xb = x + (long)b * 3072;
    for (int i = tid; i < 1728; i += 256) {
        int ci = i / 576, rem = i - ci * 576;
        int rr = rem >> 5, cc = rem & 31;
        int gr = r0 - 1 + rr;
        if ((unsigned)gr < 32u)
            tile[ci * 648 + rr * 36 + cc + 1] = quantm(xb[ci * 1024 + gr * 32 + cc], rsfx);
    }
    __syncthreads();
    const int oc0  = (tid >> 5) * 4;
    const int pxg  = tid & 31;
    const int row  = pxg >> 1;
    const int wcol = (pxg & 1) * 16;
    float acc[4][16];
    #pragma unroll
    for (int o = 0; o < 4; ++o)
        #pragma unroll
        for (int p = 0; p < 16; ++p) acc[o][p] = 0.f;
    #pragma unroll
    for (int kk = 0; kk < 9; ++kk) {
        int ci = kk / 3, ky = kk - ci * 3;
        const float* rp = tile + ci * 648 + (row + ky) * 36 + wcol;
        float wn[20];
        #pragma unroll
        for (int d = 0; d < 5; ++d) *(float4*)&wn[4 * d] = *(const float4*)&rp[4 * d];
        #pragma unroll
        for (int kx = 0; kx < 3; ++kx) {
            float4 wv = *(const float4*)&wlds[(kk * 3 + kx) * 32 + oc0];
            const float* wf = &wv.x;
            #pragma unroll
            for (int o = 0; o < 4; ++o)
                #pragma unroll
                for (int p = 0; p < 16; ++p)
                    acc[o][p] = fmaf(wn[p + kx], wf[o], acc[o][p]);
        }
    }
    float lmax = 0.f;
    #pragma unroll
    for (int o = 0; o < 4; ++o) {
        float A = As[oc0 + o], C = Cs[oc0 + o];
        #pragma unroll
        for (int p = 0; p < 16; ++p)
            lmax = fmaxf(lmax, fabsf(fmaf(acc[o][p], A, C)));
    }
    block_max_atomic(lmax, mout);
}

// ---------------- conv0 pass 2 + fused 1x1 conv1. grid 1024 ----------------
__global__ __launch_bounds__(256) void k_conv01n(
    const float* __restrict__ x, const float* __restrict__ w0p,
    const float* __restrict__ wsf0, const float* __restrict__ bias0,
    const float* __restrict__ bns0, const float* __restrict__ bnb0,
    const float* __restrict__ w1i,
    const float* __restrict__ wsf1, const float* __restrict__ bias1,
    const float* __restrict__ bns1, const float* __restrict__ bnb1,
    const unsigned* __restrict__ umax, unsigned* __restrict__ mout,
    float* __restrict__ out) {
    __shared__ float tile[3672];
    __shared__ float wls0[896];
    __shared__ float wls1[128];
    __shared__ float Aq[32], Cq[32];
    __shared__ float A1s[4], C1s[4];
    const int b   = blockIdx.x;
    const int tid = threadIdx.x;
    const float sfx = get_sf0(umax);
    const float rsfx = 1.0f / sfx;
    const float sf1 = get_sf(umax, 1);
    const float rsf1 = 1.0f / sf1;
    if (tid < 32) {
        int oc = tid;
        float bsf = wsf0[oc] * sfx;
        float bint = rintf(bias0[oc] / bsf);
        float a = bsf * bns0[oc];
        float c = fmaf(bint, a, bnb0[oc]);
        Aq[oc] = a * rsf1;
        Cq[oc] = c * rsf1;
    }
    if (tid >= 64 && tid < 68) {
        int oc = tid - 64;
        float bsf = wsf1[oc] * sf1;
        float bint = rintf(bias1[oc] / bsf);
        float a = bsf * bns1[oc];
        A1s[oc] = a;
        C1s[oc] = fmaf(bint, a, bnb1[oc]);
    }
    for (int i = tid; i < 3672; i += 256) tile[i] = 0.f;
    if (tid < 224) ((float4*)wls0)[tid] = ((const float4*)w0p)[tid];
    if (tid >= 128 && tid < 256) {
        int j = tid - 128;
        wls1[(j & 31) * 4 + (j >> 5)] = w1i[j];
    }
    __syncthreads();
    const float* xb = x + (long)b * 3072;
    for (int i = tid; i < 3072; i += 256) {
        int ci = i >> 10, px = i & 1023;
        int iy = px >> 5, ix = px & 31;
        tile[ci * 1224 + (iy + 1) * 36 + (ix + 1)] = quantm(xb[i], rsfx);
    }
    __syncthreads();
    const int h   = tid >> 3;
    const int w0c = (tid & 7) * 4;
    float win[3][3][6];
    #pragma unroll
    for (int ci = 0; ci < 3; ++ci)
        #pragma unroll
        for (int ky = 0; ky < 3; ++ky) {
            const int base = ci * 1224 + (h + ky) * 36 + w0c;
            *(float4*)&win[ci][ky][0] = *(const float4*)&tile[base];
            *(float2*)&win[ci][ky][4] = *(const float2*)&tile[base + 4];
        }
    float acc1[4][4];
    #pragma unroll
    for (int o = 0; o < 4; ++o)
        #pragma unroll
        for (int p = 0; p < 4; ++p) acc1[o][p] = 0.f;
    #pragma unroll 2
    for (int oc = 0; oc < 32; ++oc) {
        float wreg[28];
        const float4* wp4 = (const float4*)&wls0[oc * 28];
        #pragma unroll
        for (int d = 0; d < 7; ++d) *(float4*)&wreg[4 * d] = wp4[d];
        float a0 = 0.f, a1 = 0.f, a2 = 0.f, a3 = 0.f;
        #pragma unroll
        for (int ci = 0; ci < 3; ++ci)
            #pragma unroll
            for (int ky = 0; ky < 3; ++ky)
                #pragma unroll
                for (int kx = 0; kx < 3; ++kx) {
                    float wv = wreg[ci * 9 + ky * 3 + kx];
                    a0 = fmaf(win[ci][ky][kx + 0], wv, a0);
                    a1 = fmaf(win[ci][ky][kx + 1], wv, a1);
                    a2 = fmaf(win[ci][ky][kx + 2], wv, a2);
                    a3 = fmaf(win[ci][ky][kx + 3], wv, a3);
                }
        float A = Aq[oc], C = Cq[oc];
        float q0 = fminf(fmaxf(rintf(fmaf(a0, A, C)), -127.0f), 127.0f);
        float q1 = fminf(fmaxf(rintf(fmaf(a1, A, C)), -127.0f), 127.0f);
        float q2 = fminf(fmaxf(rintf(fmaf(a2, A, C)), -127.0f), 127.0f);
        float q3 = fminf(fmaxf(rintf(fmaf(a3, A, C)), -127.0f), 127.0f);
        const float4 w1v = *(const float4*)&wls1[oc * 4];
        acc1[0][0] = fmaf(q0, w1v.x, acc1[0][0]); acc1[0][1] = fmaf(q1, w1v.x, acc1[0][1]);
        acc1[0][2] = fmaf(q2, w1v.x, acc1[0][2]); acc1[0][3] = fmaf(q3, w1v.x, acc1[0][3]);
        acc1[1][0] = fmaf(q0, w1v.y, acc1[1][0]); acc1[1][1] = fmaf(q1, w1v.y, acc1[1][1]);
        acc1[1][2] = fmaf(q2, w1v.y, acc1[1][2]); acc1[1][3] = fmaf(q3, w1v.y, acc1[1][3]);
        acc1[2][0] = fmaf(q0, w1v.z, acc1[2][0]); acc1[2][1] = fmaf(q1, w1v.z, acc1[2][1]);
        acc1[2][2] = fmaf(q2, w1v.z, acc1[2][2]); acc1[2][3] = fmaf(q3, w1v.z, acc1[2][3]);
        acc1[3][0] = fmaf(q0, w1v.w, acc1[3][0]); acc1[3][1] = fmaf(q1, w1v.w, acc1[3][1]);
        acc1[3][2] = fmaf(q2, w1v.w, acc1[3][2]); acc1[3][3] = fmaf(q3, w1v.w, acc1[3][3]);
    }
    float lmax = 0.f;
    float* ob = out + (long)b * 4096 + h * 32 + w0c;
    #pragma unroll
    for (int o = 0; o < 4; ++o) {
        float y0 = fmaf(acc1[o][0], A1s[o], C1s[o]);
        float y1 = fmaf(acc1[o][1], A1s[o], C1s[o]);
        float y2 = fmaf(acc1[o][2], A1s[o], C1s[o]);
        float y3 = fmaf(acc1[o][3], A1s[o], C1s[o]);
        lmax = fmaxf(lmax, fmaxf(fmaxf(fabsf(y0), fabsf(y1)), fmaxf(fabsf(y2), fabsf(y3))));
        float4 r4; r4.x = y0; r4.y = y1; r4.z = y2; r4.w = y3;
        *(float4*)&ob[o * 1024] = r4;
    }
    block_max_atomic(lmax, mout);
}

// ---------------- conv2 (4->32, 3x3, s2): thread = 8 oc x 4 px ----------------
__global__ __launch_bounds__(256) void k_conv2c(
    const float* __restrict__ inp, const float* __restrict__ w2kt,
    const float* __restrict__ wsf, const float* __restrict__ bias,
    const float* __restrict__ bns, const float* __restrict__ bnb,
    const unsigned* __restrict__ umax, unsigned* __restrict__ mout,
    float* __restrict__ out) {
    __shared__ float tile[4 * 34 * 36];
    __shared__ float wlds[36 * 32];
    __shared__ float As[32], Cs[32];
    const int tid = threadIdx.x;
    const float sf = get_sf(umax, 2);
    const float rsf = 1.0f / sf;
    if (tid < 32) {
        int oc = tid;
        float bsf = wsf[oc] * sf;
        float bint = rintf(bias[oc] / bsf);
        float a = bsf * bns[oc];
        As[oc] = a;
        Cs[oc] = fmaf(bint, a, bnb[oc]);
    }
    for (int i = tid; i < 4896; i += 256) tile[i] = 0.f;
    for (int i = tid; i < 288; i += 256) ((float4*)wlds)[i] = ((const float4*)w2kt)[i];
    __syncthreads();
    const float* ib = inp + (long)blockIdx.x * 4096;
    for (int i = tid; i < 4096; i += 256) {
        int ci = i >> 10, px = i & 1023;
        int iy = px >> 5, ix = px & 31;
        tile[ci * 1224 + (iy + 1) * 36 + (ix + 1)] = quantm(ib[i], rsf);
    }
    __syncthreads();
    const int oc0 = (tid >> 6) * 8;
    const int pxq = tid & 63;
    const int h = pxq >> 2, c = pxq & 3;
    float acc[8][4];
    #pragma unroll
    for (int k = 0; k < 8; ++k)
        #pragma unroll
        for (int p = 0; p < 4; ++p) acc[k][p] = 0.f;
    #pragma unroll
    for (int ci = 0; ci < 4; ++ci) {
        #pragma unroll
        for (int ky = 0; ky < 3; ++ky) {
            const float* rp = tile + ci * 1224 + (2 * h + ky) * 36 + 8 * c;
            float wn[12];
            #pragma unroll
            for (int d = 0; d < 3; ++d) *(float4*)&wn[4 * d] = *(const float4*)&rp[4 * d];
            #pragma unroll
            for (int kx = 0; kx < 3; ++kx) {
                const float* wp = &wlds[(ci * 9 + ky * 3 + kx) * 32 + oc0];
                float4 wa = *(const float4*)&wp[0];
                float4 wb = *(const float4*)&wp[4];
                float wf[8] = {wa.x, wa.y, wa.z, wa.w, wb.x, wb.y, wb.z, wb.w};
                #pragma unroll
                for (int k = 0; k < 8; ++k)
                    #pragma unroll
                    for (int p = 0; p < 4; ++p)
                        acc[k][p] = fmaf(wn[2 * p + kx], wf[k], acc[k][p]);
            }
        }
    }
    float lmax = 0.f;
    float* ob = out + (long)blockIdx.x * 8192;
    #pragma unroll
    for (int k = 0; k < 8; ++k) {
        int oc = oc0 + k;
        float A = As[oc], C = Cs[oc];
        float4 r;
        float* rp = &r.x;
        #pragma unroll
        for (int p = 0; p < 4; ++p) {
            float y = fmaf(acc[k][p], A, C);
            rp[p] = y;
            lmax = fmaxf(lmax, fabsf(y));
        }
        *(float4*)&ob[oc * 256 + h * 16 + c * 4] = r;
    }
    block_max_atomic(lmax, mout);
}

// ---------------- conv3/conv4 (R17-proven): 2 img/block, 256 thr, 4oc x 4px ----------------
template<int HIN, int S>
__global__ __launch_bounds__(256) void k_conv34d(
    const float* __restrict__ inp, const float* __restrict__ wt,
    const float* __restrict__ wsf, const float* __restrict__ bias,
    const float* __restrict__ bns, const float* __restrict__ bnb,
    const unsigned* __restrict__ umax, int slot, unsigned* __restrict__ mout,
    float* __restrict__ out) {
    constexpr int ROWS = HIN + 2;
    constexpr int RS   = (S == 2) ? 20 : 12;
    constexpr int TI   = 8 * ROWS * RS;
    constexpr int PIX  = HIN * HIN;
    constexpr int PSH  = (HIN == 16) ? 8 : 6;
    constexpr int HSH  = (HIN == 16) ? 4 : 3;
    constexpr int NELT = 2 * 8 * PIX;
    constexpr int WINW = (S == 2) ? 12 : 8;
    constexpr int ND   = (S == 2) ? 3 : 2;
    __shared__ float tile[2 * TI];
    __shared__ float wlds[2592];
    __shared__ float As[32], Cs[32];
    const int tid  = threadIdx.x;
    const int imgl = tid >> 7;
    const int ocg  = (tid >> 4) & 7;
    const int pxq  = tid & 15;
    const int h = pxq >> 1, c = pxq & 1;
    const float sf = get_sf(umax, slot);
    const float rsf = 1.0f / sf;
    if (tid < 32) {
        int oc = tid;
        float bsf = wsf[oc] * sf;
        float bint = rintf(bias[oc] / bsf);
        float a = bsf * bns[oc];
        As[oc] = a;
        Cs[oc] = fmaf(bint, a, bnb[oc]);
    }
    for (int i = tid; i < 2 * TI; i += 256) tile[i] = 0.f;
    float acc[4][4];
    #pragma unroll
    for (int k = 0; k < 4; ++k)
        #pragma unroll
        for (int p = 0; p < 4; ++p) acc[k][p] = 0.f;
    const float* ib = inp + (long)blockIdx.x * 2 * 32 * PIX;
    const float4* wt4 = (const float4*)wt;
    for (int ph = 0; ph < 4; ++ph) {
        __syncthreads();
        for (int i = tid; i < NELT; i += 256) {
            int im = i >> (PSH + 3);
            int ci = (i >> PSH) & 7;
            int px = i & (PIX - 1);
            int iy = px >> HSH, ix = px & (HIN - 1);
            tile[im * TI + ci * (ROWS * RS) + (iy + 1) * RS + (ix + 1)] =
                quantm(ib[(long)((im * 32 + ph * 8 + ci) << PSH) + px], rsf);
        }
        for (int i = tid; i < 648; i += 256) ((float4*)wlds)[i] = wt4[ph * 648 + i];
        __syncthreads();
        const int tbo = imgl * TI;
        #pragma unroll
        for (int ci = 0; ci < 8; ++ci) {
            float win[3][WINW];
            #pragma unroll
            for (int ky = 0; ky < 3; ++ky) {
                const int base = tbo + ci * (ROWS * RS) + (S * h + ky) * RS + S * 4 * c;
                #pragma unroll
                for (int d = 0; d < ND; ++d)
                    *(float4*)&win[ky][4 * d] = *(const float4*)&tile[base + 4 * d];
            }
            #pragma unroll
            for (int ky = 0; ky < 3; ++ky)
                #pragma unroll
                for (int kx = 0; kx < 3; ++kx) {
                    int j = ky * 3 + kx;
                    float4 wv = *(const float4*)&wlds[(ci * 9 + j) * 36 + ocg * 4];
                    float x0 = win[ky][S * 0 + kx];
                    float x1 = win[ky][S * 1 + kx];
                    float x2 = win[ky][S * 2 + kx];
                    float x3 = win[ky][S * 3 + kx];
                    acc[0][0] = fmaf(x0, wv.x, acc[0][0]); acc[0][1] = fmaf(x1, wv.x, acc[0][1]);
                    acc[0][2] = fmaf(x2, wv.x, acc[0][2]); acc[0][3] = fmaf(x3, wv.x, acc[0][3]);
                    acc[1][0] = fmaf(x0, wv.y, acc[1][0]); acc[1][1] = fmaf(x1, wv.y, acc[1][1]);
                    acc[1][2] = fmaf(x2, wv.y, acc[1][2]); acc[1][3] = fmaf(x3, wv.y, acc[1][3]);
                    acc[2][0] = fmaf(x0, wv.z, acc[2][0]); acc[2][1] = fmaf(x1, wv.z, acc[2][1]);
                    acc[2][2] = fmaf(x2, wv.z, acc[2][2]); acc[2][3] = fmaf(x3, wv.z, acc[2][3]);
                    acc[3][0] = fmaf(x0, wv.w, acc[3][0]); acc[3][1] = fmaf(x1, wv.w, acc[3][1]);
                    acc[3][2] = fmaf(x2, wv.w, acc[3][2]); acc[3][3] = fmaf(x3, wv.w, acc[3][3]);
                }
        }
    }
    float lmax = 0.f;
    long imgg = (long)blockIdx.x * 2 + imgl;
    #pragma unroll
    for (int k = 0; k < 4; ++k) {
        int oc = ocg * 4 + k;
        float A = As[oc], C = Cs[oc];
        float y0 = fmaf(acc[k][0], A, C);
        float y1 = fmaf(acc[k][1], A, C);
        float y2 = fmaf(acc[k][2], A, C);
        float y3 = fmaf(acc[k][3], A, C);
        lmax = fmaxf(lmax, fmaxf(fmaxf(fabsf(y0), fabsf(y1)), fmaxf(fabsf(y2), fabsf(y3))));
        float4 r4; r4.x = y0; r4.y = y1; r4.z = y2; r4.w = y3;
        *(float4*)&out[(imgg * 32 + oc) * 64 + h * 8 + c * 4] = r4;
    }
    block_max_atomic(lmax, mout);
}

// ---------------- linear 2048->10 per image ----------------
__global__ __launch_bounds__(256) void k_fc(
    const float* __restrict__ act, const float* __restrict__ wdi,
    const float* __restrict__ wsfd, const float* __restrict__ bd,
    const unsigned* __restrict__ umax, float* __restrict__ logits) {
    int b = blockIdx.x;
    float sf = get_sf(umax, 5);
    float rsf = 1.0f / sf;
    const float* ab = act + (long)b * 2048;
    float acc[10];
    #pragma unroll
    for (int c = 0; c < 10; ++c) acc[c] = 0.f;
    #pragma unroll
    for (int k = 0; k < 8; ++k) {
        int j = threadIdx.x + 256 * k;
        float q = quantm(ab[j], rsf);
        #pragma unroll
        for (int c = 0; c < 10; ++c) acc[c] = fmaf(q, wdi[c * 2048 + j], acc[c]);
    }
    #pragma unroll
    for (int c = 0; c < 10; ++c)
        #pragma unroll
        for (int o = 32; o; o >>= 1) acc[c] += __shfl_down(acc[c], o, 64);
    __shared__ float red[4][10];
    int wid = threadIdx.x >> 6;
    if ((threadIdx.x & 63) == 0)
        #pragma unroll
        for (int c = 0; c < 10; ++c) red[wid][c] = acc[c];
    __syncthreads();
    if (threadIdx.x < 10) {
        int c = threadIdx.x;
        float s = red[0][c] + red[1][c] + red[2][c] + red[3][c];
        float bsf = wsfd[c] * sf;
        float bint = rintf(bd[c] / bsf);
        logits[b * 10 + c] = (s + bint) * bsf;
    }
}

// ---------------- softmax over batch axis (dim 0) ----------------
__global__ __launch_bounds__(256) void k_softmax(const float* __restrict__ logits, float* __restrict__ out) {
    int c = blockIdx.x;
    float v0 = logits[(threadIdx.x +   0) * 10 + c];
    float v1 = logits[(threadIdx.x + 256) * 10 + c];
    float v2 = logits[(threadIdx.x + 512) * 10 + c];
    float v3 = logits[(threadIdx.x + 768) * 10 + c];
    float mx = fmaxf(fmaxf(v0, v1), fmaxf(v2, v3));
    __shared__ float redm[4];
    __shared__ float reds[4];
    #pragma unroll
    for (int o = 32; o; o >>= 1) mx = fmaxf(mx, __shfl_down(mx, o, 64));
    if ((threadIdx.x & 63) == 0) redm[threadIdx.x >> 6] = mx;
    __syncthreads();
    mx = fmaxf(fmaxf(redm[0], redm[1]), fmaxf(redm[2], redm[3]));
    float e0 = expf(v0 - mx), e1 = expf(v1 - mx), e2 = expf(v2 - mx), e3 = expf(v3 - mx);
    float s = (e0 + e1) + (e2 + e3);
    #pragma unroll
    for (int o = 32; o; o >>= 1) s += __shfl_down(s, o, 64);
    if ((threadIdx.x & 63) == 0) reds[threadIdx.x >> 6] = s;
    __syncthreads();
    s = reds[0] + reds[1] + reds[2] + reds[3];
    out[(threadIdx.x +   0) * 10 + c] = e0 / s;
    out[(threadIdx.x + 256) * 10 + c] = e1 / s;
    out[(threadIdx.x + 512) * 10 + c] = e2 / s;
    out[(threadIdx.x + 768) * 10 + c] = e3 / s;
}

extern "C" void kernel_launch(void* const* d_in, const int* in_sizes, int n_in,
                              void* d_out, int out_size, void* d_ws, size_t ws_size,
                              hipStream_t stream) {
    (void)in_sizes; (void)n_in; (void)out_size; (void)ws_size;
    const float* x = (const float*)d_in[0];
    const float *w[5], *bia[5], *g[5], *bb[5], *m[5], *v[5];
    for (int i = 0; i < 5; ++i) {
        w[i]   = (const float*)d_in[1 + 6 * i + 0];
        bia[i] = (const float*)d_in[1 + 6 * i + 1];
        g[i]   = (const float*)d_in[1 + 6 * i + 2];
        bb[i]  = (const float*)d_in[1 + 6 * i + 3];
        m[i]   = (const float*)d_in[1 + 6 * i + 4];
        v[i]   = (const float*)d_in[1 + 6 * i + 5];
    }
    const float* wd = (const float*)d_in[31];
    const float* bd = (const float*)d_in[32];
    float* ws = (float*)d_ws;
    unsigned* umax = (unsigned*)ws;   // [256] slot0 + [5][64] slots1-5
    float* out = (float*)d_out;

    float* w0kt = ws + OFF_W0KT;
    float* w0p  = ws + OFF_W0P;
    float* w1i  = ws + OFF_W1I;
    float* w2kt = ws + OFF_W2KT;
    float* w3t  = ws + OFF_W3T;
    float* w4t  = ws + OFF_W4T;
    float* wdi  = ws + OFF_WDI;
    float* wsf0 = ws + OFF_WSF0; float* bns0 = ws + OFF_BNS0; float* bnb0 = ws + OFF_BNB0;
    float* wsf1 = ws + OFF_WSF1; float* bns1 = ws + OFF_BNS1; float* bnb1 = ws + OFF_BNB1;
    float* wsf2 = ws + OFF_WSF2; float* bns2 = ws + OFF_BNS2; float* bnb2 = ws + OFF_BNB2;
    float* wsf3 = ws + OFF_WSF3; float* bns3 = ws + OFF_BNS3; float* bnb3 = ws + OFF_BNB3;
    float* wsf4 = ws + OFF_WSF4; float* bns4 = ws + OFF_BNS4; float* bnb4 = ws + OFF_BNB4;
    float* wsfd = ws + OFF_WSFD;
    float* logits = ws + OFF_LOG;
    float* actA = ws + ACT_A_OFF;   // act2 / act4
    float* actB = ws + ACT_B_OFF;   // act1 / act3

    PrepAll pa;
    pa.umax = umax;
    pa.x = (const float4*)x;
    const float* ww[6] = {w[0], w[1], w[2], w[3], w[4], wd};
    float* wsfp[6] = {wsf0, wsf1, wsf2, wsf3, wsf4, wsfd};
    float* dstp[6] = {w0kt, w1i, w2kt, w3t, w4t, wdi};
    float* dst2p[6] = {w0p, nullptr, nullptr, nullptr, nullptr, nullptr};
    float* bnsp[6] = {bns0, bns1, bns2, bns3, bns4, nullptr};
    float* bnbp[6] = {bnb0, bnb1, bnb2, bnb3, bnb4, nullptr};
    int Ks[6]   = {27, 32, 36, 288, 288, 2048};
    int modes[6] = {2, 0, 1, 3, 3, 0};
    for (int i = 0; i < 6; ++i) {
        pa.e[i].w = ww[i];
        pa.e[i].g = (i < 5) ? g[i] : nullptr;
        pa.e[i].bb = (i < 5) ? bb[i] : nullptr;
        pa.e[i].m = (i < 5) ? m[i] : nullptr;
        pa.e[i].v = (i < 5) ? v[i] : nullptr;
        pa.e[i].wsf = wsfp[i];
        pa.e[i].dst = dstp[i];
        pa.e[i].dst2 = dst2p[i];
        pa.e[i].bns = bnsp[i];
        pa.e[i].bnb = bnbp[i];
        pa.e[i].K = Ks[i];
        pa.e[i].has_bn = (i < 5) ? 1 : 0;
        pa.e[i].mode = modes[i];
    }

    hipLaunchKernelGGL(k_prep_all, dim3(399), dim3(256), 0, stream, pa);
    hipLaunchKernelGGL(k_conv0maxN, dim3(2048), dim3(256), 0, stream,
                       x, w0kt, wsf0, bia[0], bns0, bnb0, umax, umax + 256);
    hipLaunchKernelGGL(k_conv01n, dim3(1024), dim3(256), 0, stream,
                       x, w0p, wsf0, bia[0], bns0, bnb0,
                       w1i, wsf1, bia[1], bns1, bnb1, umax, umax + 320, actB);
    hipLaunchKernelGGL(k_conv2c, dim3(1024), dim3(256), 0, stream,
                       actB, w2kt, wsf2, bia[2], bns2, bnb2, umax, umax + 384, actA);
    hipLaunchKernelGGL((k_conv34d<16, 2>), dim3(512), dim3(256), 0, stream,
                       actA, w3t, wsf3, bia[3], bns3, bnb3, umax, 3, umax + 448, actB);
    hipLaunchKernelGGL((k_conv34d<8, 1>),  dim3(512), dim3(256), 0, stream,
                       actB, w4t, wsf4, bia[4], bns4, bnb4, umax, 4, umax + 512, actA);
    hipLaunchKernelGGL(k_fc, dim3(1024), dim3(256), 0, stream, actA, wdi, wsfd, bd, umax, logits);
    hipLaunchKernelGGL(k_softmax, dim3(10), dim3(256), 0, stream, logits, out);
}